// Round 7
// baseline (189.780 us; speedup 1.0000x reference)
//
#include <hip/hip_runtime.h>

#define B_    32
#define N_    10000
#define G_    256
#define HID_  256
#define EPS_  1e-5f

// prep_k grid segmentation
#define TB_W1  2504            // 313 col-tiles x 8 row-tiles (W1: 256 x 10000)
#define TB_X   313             // x: 32 x 10000
#define TB_W2  64              // W2: 256 x 256
#define NB_CMP 256             // mask compaction, one block per g
#define PREP_GRID (TB_W1 + TB_X + TB_W2 + NB_CMP)   // 3137

#define DKB_  40               // dense-group split-K producer blocks
#define DCH_  250              // genes per dense chunk (40*250 = 10000)
// mega grid: 40 dense producers | 255 sparse producers | 255 sparse consumers | 1 dense consumer
#define MEGA_GRID (DKB_ + 255 + 255 + 1)   // 551

// ---------------------------------------------------------------------------
// Tiled transpose helper: src R x C row-major -> dst C x R row-major.
// ---------------------------------------------------------------------------
__device__ inline void transpose_tile(const float* __restrict__ src,
                                      float* __restrict__ dst,
                                      int R, int C, int bx, int by, int t,
                                      float (*tile)[33]) {
    int tx = t & 31, ty = t >> 5;      // 32 x 8
    int c0 = bx * 32, r0 = by * 32;
#pragma unroll
    for (int j = 0; j < 4; ++j) {
        int r = r0 + ty + j * 8, c = c0 + tx;
        if (r < R && c < C) tile[ty + j * 8][tx] = src[(size_t)r * C + c];
    }
    __syncthreads();
#pragma unroll
    for (int j = 0; j < 4; ++j) {
        int c = c0 + ty + j * 8, r = r0 + tx;
        if (r < R && c < C) dst[(size_t)c * R + r] = tile[tx][ty + j * 8];
    }
}

// ---------------------------------------------------------------------------
// Fused prep: transposes + mask compaction + sync-flag reset.
// ---------------------------------------------------------------------------
__global__ __launch_bounds__(256) void prep_k(const float* __restrict__ W1,
                                              const float* __restrict__ x,
                                              const float* __restrict__ W2,
                                              const float* __restrict__ mask,
                                              float* __restrict__ w1t,
                                              float* __restrict__ xt,
                                              float* __restrict__ w2t,
                                              int* __restrict__ cnt,
                                              unsigned short* __restrict__ idx,
                                              int* __restrict__ ctr,
                                              int* __restrict__ flags) {
    __shared__ float tile[32][33];
    __shared__ int c;
    int bid = blockIdx.x, t = threadIdx.x;

    if (bid == 0) {                    // reset mega_k sync state every call
        if (t == 0) *ctr = 0;
        flags[t] = 0;                  // 256 flags, block is 256 threads
    }

    if (bid < TB_W1) {
        transpose_tile(W1, w1t, HID_, N_, bid % 313, bid / 313, t, tile);
    } else if (bid < TB_W1 + TB_X) {
        transpose_tile(x, xt, B_, N_, bid - TB_W1, 0, t, tile);
    } else if (bid < TB_W1 + TB_X + TB_W2) {
        int b = bid - (TB_W1 + TB_X);
        transpose_tile(W2, w2t, 256, HID_, b % 8, b / 8, t, tile);
    } else {
        int g = bid - (TB_W1 + TB_X + TB_W2);
        if (t == 0) c = 0;
        __syncthreads();
        for (int n = t; n < N_; n += 256) {
            if (mask[(size_t)g * N_ + n] != 0.0f) {
                int p = atomicAdd(&c, 1);          // LDS atomic only
                idx[(size_t)g * N_ + p] = (unsigned short)n;
            }
        }
        __syncthreads();
        if (t == 0) cnt[g] = c;
    }
}

// ---------------------------------------------------------------------------
// 16 scalar FMAs: acc[j] (batch 4tb+j) += x[j] * w  (float4 over HID cols)
// ---------------------------------------------------------------------------
__device__ __forceinline__ void fma16(float4& a0, float4& a1, float4& a2,
                                      float4& a3, float4 w, float4 xv) {
    a0.x = fmaf(xv.x, w.x, a0.x); a0.y = fmaf(xv.x, w.y, a0.y);
    a0.z = fmaf(xv.x, w.z, a0.z); a0.w = fmaf(xv.x, w.w, a0.w);
    a1.x = fmaf(xv.y, w.x, a1.x); a1.y = fmaf(xv.y, w.y, a1.y);
    a1.z = fmaf(xv.y, w.z, a1.z); a1.w = fmaf(xv.y, w.w, a1.w);
    a2.x = fmaf(xv.z, w.x, a2.x); a2.y = fmaf(xv.z, w.y, a2.y);
    a2.z = fmaf(xv.z, w.z, a2.z); a2.w = fmaf(xv.z, w.w, a2.w);
    a3.x = fmaf(xv.w, w.x, a3.x); a3.y = fmaf(xv.w, w.y, a3.y);
    a3.z = fmaf(xv.w, w.z, a3.z); a3.w = fmaf(xv.w, w.w, a3.w);
}

// ---------------------------------------------------------------------------
// MEGA kernel, barrier-free GEMM1 (no LDS staging):
//   bid <  40      : dense producer (group 255, 250 genes)  -> hpartD, ctr++
//   bid 40..294    : sparse producer g=bid-40, genes [0,mid) -> hpartS, flag=1
//   bid 295..549   : sparse consumer g=bid-295, genes [mid,cnt), merge,
//                    then BN1 -> GEMM2 -> BN2 -> out
//   bid == 550     : dense consumer (group 255): reduce 40 partials, same tail
// 512 threads: tc=t&63 (float4 col; wave spans full 1KB W row, coalesced),
//              tb=t>>6 (batches 4tb..4tb+3; x loads wave-uniform, L1-served).
// launch_bounds(512,6) -> VGPR<=85 -> >=3 blocks/CU -> all 551 co-resident
// (LDS 33.4KB -> 4/CU; waves 32/CU -> 4/CU) => spin-waits are deadlock-free.
// ---------------------------------------------------------------------------
__global__ __launch_bounds__(512, 6) void mega_k(const float4* __restrict__ w1t4,
                                                 const float4* __restrict__ xt4,
                                                 const int* __restrict__ cnt,
                                                 const unsigned short* __restrict__ idx,
                                                 const float4* __restrict__ b1_4,
                                                 const float* __restrict__ g1,
                                                 const float* __restrict__ be1,
                                                 const float4* __restrict__ w2t4,
                                                 const float4* __restrict__ b2_4,
                                                 const float* __restrict__ g2,
                                                 const float* __restrict__ be2,
                                                 float4* __restrict__ hpartD,
                                                 float4* __restrict__ hpartS,
                                                 int* __restrict__ ctr,
                                                 int* __restrict__ flags,
                                                 float4* __restrict__ z4) {
    __shared__ float lh[32][260];      // 33.3 KB, only used in phases B/C
    __shared__ float rs[8], rss[8];
    const int bid = blockIdx.x, t = threadIdx.x;
    const int tc = t & 63;             // float4 column 0..63
    const int tb = t >> 6;             // wave id -> batches 4tb..4tb+3

    float4 a0 = make_float4(0.f, 0.f, 0.f, 0.f), a1 = a0, a2 = a0, a3 = a0;

    auto gene4 = [&](int n0, int n1, int n2, int n3) {
        float4 w0 = w1t4[(size_t)n0 * 64 + tc];
        float4 w1 = w1t4[(size_t)n1 * 64 + tc];
        float4 w2 = w1t4[(size_t)n2 * 64 + tc];
        float4 w3 = w1t4[(size_t)n3 * 64 + tc];
        float4 x0 = xt4[(size_t)n0 * 8 + tb];
        float4 x1 = xt4[(size_t)n1 * 8 + tb];
        float4 x2 = xt4[(size_t)n2 * 8 + tb];
        float4 x3 = xt4[(size_t)n3 * 8 + tb];
        fma16(a0, a1, a2, a3, w0, x0);
        fma16(a0, a1, a2, a3, w1, x1);
        fma16(a0, a1, a2, a3, w2, x2);
        fma16(a0, a1, a2, a3, w3, x3);
    };
    auto gene1 = [&](int n) {
        float4 w = w1t4[(size_t)n * 64 + tc];
        float4 xv = xt4[(size_t)n * 8 + tb];
        fma16(a0, a1, a2, a3, w, xv);
    };
    // sparse K-range [ks, ke) via idx; ks must be a multiple of 8.
    auto runIdx = [&](const unsigned short* idxp, int ks, int ke) {
        int kk = ks;
        int kmain = ks + ((ke - ks) & ~7);
        for (; kk < kmain; kk += 8) {
            uint4 ip = *(const uint4*)(idxp + kk);   // wave-uniform 16B, 8 idx
            gene4((int)(ip.x & 0xffff), (int)(ip.x >> 16),
                  (int)(ip.y & 0xffff), (int)(ip.y >> 16));
            gene4((int)(ip.z & 0xffff), (int)(ip.z >> 16),
                  (int)(ip.w & 0xffff), (int)(ip.w >> 16));
        }
        for (; kk < ke; ++kk) gene1((int)idxp[kk]);
    };

    int g;
    if (bid < DKB_) {
        // -------- dense producer: contiguous genes, no idx --------
        g = 255;
        int k0 = bid * DCH_, kend = k0 + DCH_;
        int k = k0;
        for (; k + 4 <= kend; k += 4) gene4(k, k + 1, k + 2, k + 3);
        for (; k < kend; ++k) gene1(k);
        float4* dst = hpartD + (size_t)bid * 2048;
        dst[(4 * tb + 0) * 64 + tc] = a0;
        dst[(4 * tb + 1) * 64 + tc] = a1;
        dst[(4 * tb + 2) * 64 + tc] = a2;
        dst[(4 * tb + 3) * 64 + tc] = a3;
        __threadfence();
        __syncthreads();
        if (t == 0)
            __hip_atomic_fetch_add(ctr, 1, __ATOMIC_RELEASE,
                                   __HIP_MEMORY_SCOPE_AGENT);
        return;
    } else if (bid < DKB_ + 255) {
        // -------- sparse producer: genes [0, mid) --------
        g = bid - DKB_;
        int c = cnt[g];
        int mid = (c >> 1) & ~7;
        runIdx(idx + (size_t)g * N_, 0, mid);
        float4* dst = hpartS + (size_t)g * 2048;
        dst[(4 * tb + 0) * 64 + tc] = a0;
        dst[(4 * tb + 1) * 64 + tc] = a1;
        dst[(4 * tb + 2) * 64 + tc] = a2;
        dst[(4 * tb + 3) * 64 + tc] = a3;
        __threadfence();
        __syncthreads();
        if (t == 0)
            __hip_atomic_store(&flags[g], 1, __ATOMIC_RELEASE,
                               __HIP_MEMORY_SCOPE_AGENT);
        return;
    } else if (bid < DKB_ + 510) {
        // -------- sparse consumer: genes [mid, cnt), then merge --------
        g = bid - (DKB_ + 255);
        int c = cnt[g];
        int mid = (c >> 1) & ~7;
        runIdx(idx + (size_t)g * N_, mid, c);
        float4 bb = b1_4[tc];
        a0.x += bb.x; a0.y += bb.y; a0.z += bb.z; a0.w += bb.w;
        a1.x += bb.x; a1.y += bb.y; a1.z += bb.z; a1.w += bb.w;
        a2.x += bb.x; a2.y += bb.y; a2.z += bb.z; a2.w += bb.w;
        a3.x += bb.x; a3.y += bb.y; a3.z += bb.z; a3.w += bb.w;
        if (t == 0) {
            while (__hip_atomic_load(&flags[g], __ATOMIC_ACQUIRE,
                                     __HIP_MEMORY_SCOPE_AGENT) == 0)
                __builtin_amdgcn_s_sleep(1);
            __threadfence();
        }
        __syncthreads();
        const float4* pp = hpartS + (size_t)g * 2048;
        float4 p0 = pp[(4 * tb + 0) * 64 + tc];
        float4 p1 = pp[(4 * tb + 1) * 64 + tc];
        float4 p2 = pp[(4 * tb + 2) * 64 + tc];
        float4 p3 = pp[(4 * tb + 3) * 64 + tc];
        a0.x += p0.x; a0.y += p0.y; a0.z += p0.z; a0.w += p0.w;
        a1.x += p1.x; a1.y += p1.y; a1.z += p1.z; a1.w += p1.w;
        a2.x += p2.x; a2.y += p2.y; a2.z += p2.z; a2.w += p2.w;
        a3.x += p3.x; a3.y += p3.y; a3.z += p3.z; a3.w += p3.w;
    } else {
        // -------- dense consumer: reduce 40 partials --------
        g = 255;
        if (t == 0) {
            while (__hip_atomic_load(ctr, __ATOMIC_ACQUIRE,
                                     __HIP_MEMORY_SCOPE_AGENT) < DKB_)
                __builtin_amdgcn_s_sleep(1);
            __threadfence();
        }
        __syncthreads();
        float4 bb = b1_4[tc];
        a0 = bb; a1 = bb; a2 = bb; a3 = bb;
#pragma unroll 4
        for (int kb = 0; kb < DKB_; ++kb) {
            const float4* pp = hpartD + (size_t)kb * 2048 + (4 * tb) * 64 + tc;
            float4 v0 = pp[0], v1 = pp[64], v2 = pp[128], v3 = pp[192];
            a0.x += v0.x; a0.y += v0.y; a0.z += v0.z; a0.w += v0.w;
            a1.x += v1.x; a1.y += v1.y; a1.z += v1.z; a1.w += v1.w;
            a2.x += v2.x; a2.y += v2.y; a2.z += v2.z; a2.w += v2.w;
            a3.x += v3.x; a3.y += v3.y; a3.z += v3.z; a3.w += v3.w;
        }
    }

    // ---------------- phase B: BN1 stats (from registers) ----------------
    float s = 0.f, ss = 0.f;
    {
        float4 aa[4] = {a0, a1, a2, a3};
#pragma unroll
        for (int j = 0; j < 4; ++j) {
            s  += aa[j].x + aa[j].y + aa[j].z + aa[j].w;
            ss += aa[j].x * aa[j].x + aa[j].y * aa[j].y
                + aa[j].z * aa[j].z + aa[j].w * aa[j].w;
        }
    }
#pragma unroll
    for (int o = 32; o > 0; o >>= 1) { s += __shfl_down(s, o); ss += __shfl_down(ss, o); }
    if (tc == 0) { rs[tb] = s; rss[tb] = ss; }
    __syncthreads();
    float S = 0.f, SS = 0.f;
#pragma unroll
    for (int j = 0; j < 8; ++j) { S += rs[j]; SS += rss[j]; }
    const float inv = 1.0f / (float)(B_ * HID_);
    float mean = S * inv;
    float var  = SS * inv - mean * mean;       // biased, matches jnp.var
    float sc = g1[g] * rsqrtf(var + EPS_);
    float sh = be1[g] - mean * sc;

    // normalize + ReLU own elements -> LDS
    {
        float4 aa[4] = {a0, a1, a2, a3};
#pragma unroll
        for (int j = 0; j < 4; ++j) {
            float4 v;
            v.x = fmaxf(fmaf(aa[j].x, sc, sh), 0.f);
            v.y = fmaxf(fmaf(aa[j].y, sc, sh), 0.f);
            v.z = fmaxf(fmaf(aa[j].z, sc, sh), 0.f);
            v.w = fmaxf(fmaf(aa[j].w, sc, sh), 0.f);
            *(float4*)&lh[4 * tb + j][4 * tc] = v;
        }
    }
    __syncthreads();

    // ---------------- phase C: GEMM2 + BN2 + ReLU ----------------
    float4 bb2 = b2_4[tc];
    float4 c0 = bb2, c1 = bb2, c2 = bb2, c3 = bb2;
#pragma unroll 8
    for (int k = 0; k < HID_; ++k) {
        float4 wv = w2t4[(size_t)k * 64 + tc];         // 1KB/wave, coalesced
        float x0 = lh[4 * tb + 0][k];                  // LDS broadcast
        float x1 = lh[4 * tb + 1][k];
        float x2 = lh[4 * tb + 2][k];
        float x3 = lh[4 * tb + 3][k];
        c0.x = fmaf(x0, wv.x, c0.x); c0.y = fmaf(x0, wv.y, c0.y);
        c0.z = fmaf(x0, wv.z, c0.z); c0.w = fmaf(x0, wv.w, c0.w);
        c1.x = fmaf(x1, wv.x, c1.x); c1.y = fmaf(x1, wv.y, c1.y);
        c1.z = fmaf(x1, wv.z, c1.z); c1.w = fmaf(x1, wv.w, c1.w);
        c2.x = fmaf(x2, wv.x, c2.x); c2.y = fmaf(x2, wv.y, c2.y);
        c2.z = fmaf(x2, wv.z, c2.z); c2.w = fmaf(x2, wv.w, c2.w);
        c3.x = fmaf(x3, wv.x, c3.x); c3.y = fmaf(x3, wv.y, c3.y);
        c3.z = fmaf(x3, wv.z, c3.z); c3.w = fmaf(x3, wv.w, c3.w);
    }

    s = 0.f; ss = 0.f;
    {
        float4 cc[4] = {c0, c1, c2, c3};
#pragma unroll
        for (int j = 0; j < 4; ++j) {
            s  += cc[j].x + cc[j].y + cc[j].z + cc[j].w;
            ss += cc[j].x * cc[j].x + cc[j].y * cc[j].y
                + cc[j].z * cc[j].z + cc[j].w * cc[j].w;
        }
    }
#pragma unroll
    for (int o = 32; o > 0; o >>= 1) { s += __shfl_down(s, o); ss += __shfl_down(ss, o); }
    if (tc == 0) { rs[tb] = s; rss[tb] = ss; }   // safe: BN1 reads pre-barrier
    __syncthreads();
    S = 0.f; SS = 0.f;
#pragma unroll
    for (int j = 0; j < 8; ++j) { S += rs[j]; SS += rss[j]; }
    mean = S * inv;
    var  = SS * inv - mean * mean;
    float sc2 = g2[g] * rsqrtf(var + EPS_);
    float sh2 = be2[g] - mean * sc2;

    {
        float4 cc[4] = {c0, c1, c2, c3};
#pragma unroll
        for (int j = 0; j < 4; ++j) {
            int b = 4 * tb + j;
            float4 v;
            v.x = fmaxf(fmaf(cc[j].x, sc2, sh2), 0.f);
            v.y = fmaxf(fmaf(cc[j].y, sc2, sh2), 0.f);
            v.z = fmaxf(fmaf(cc[j].z, sc2, sh2), 0.f);
            v.w = fmaxf(fmaf(cc[j].w, sc2, sh2), 0.f);
            z4[(size_t)(b * G_ + g) * 64 + tc] = v;
        }
    }
}

// ---------------------------------------------------------------------------
extern "C" void kernel_launch(void* const* d_in, const int* in_sizes, int n_in,
                              void* d_out, int out_size, void* d_ws, size_t ws_size,
                              hipStream_t stream) {
    const float* x    = (const float*)d_in[0];
    const float* mask = (const float*)d_in[1];
    const float* W1   = (const float*)d_in[2];
    const float* b1   = (const float*)d_in[3];
    const float* g1   = (const float*)d_in[4];
    const float* be1  = (const float*)d_in[5];
    const float* W2   = (const float*)d_in[6];
    const float* b2   = (const float*)d_in[7];
    const float* g2   = (const float*)d_in[8];
    const float* be2  = (const float*)d_in[9];
    float* out = (float*)d_out;

    char* ws = (char*)d_ws;
    size_t off = 0;
    auto take = [&](size_t bytes) {
        char* p = ws + off;
        off = (off + bytes + 255) & ~(size_t)255;
        return p;
    };
    float* w1t          = (float*)take((size_t)N_ * HID_ * 4);       // (N, HID)
    float* xt           = (float*)take((size_t)N_ * B_ * 4);         // (N, B)
    float* w2t          = (float*)take((size_t)HID_ * HID_ * 4);     // (HID, Z)
    float* hpartD       = (float*)take((size_t)DKB_ * B_ * HID_ * 4);
    float* hpartS       = (float*)take((size_t)255 * B_ * HID_ * 4);
    int* cnt            = (int*)take((size_t)G_ * 4);
    unsigned short* idx = (unsigned short*)take((size_t)G_ * N_ * 2);
    int* ctr            = (int*)take(256);
    int* flags          = (int*)take((size_t)256 * 4);

    prep_k<<<PREP_GRID, 256, 0, stream>>>(W1, x, W2, mask, w1t, xt, w2t,
                                          cnt, idx, ctr, flags);
    mega_k<<<MEGA_GRID, 512, 0, stream>>>((const float4*)w1t, (const float4*)xt,
                                          cnt, idx, (const float4*)b1,
                                          g1, be1,
                                          (const float4*)w2t, (const float4*)b2,
                                          g2, be2,
                                          (float4*)hpartD, (float4*)hpartS,
                                          ctr, flags, (float4*)out);
}

// Round 8
// 158.140 us; speedup vs baseline: 1.2001x; 1.2001x over previous
//
#include <hip/hip_runtime.h>
#include <hip/hip_bf16.h>

#define B_    32
#define N_    10000
#define G_    256
#define HID_  256
#define EPS_  1e-5f

// prep_k grid segmentation
#define TB_W1  2504            // 313 col-tiles x 8 row-tiles (W1: 256 x 10000)
#define TB_X   313             // x: 32 x 10000
#define TB_W2  64              // W2: 256 x 256
#define NB_CMP 256             // mask compaction, one block per g
#define PREP_GRID (TB_W1 + TB_X + TB_W2 + NB_CMP)   // 3137

#define DKB_  40               // dense-group split-K producer blocks
#define DCH_  250              // genes per dense chunk (40*250 = 10000)
// mega grid: 40 dense producers | 255 sparse producers | 255 sparse consumers | 1 dense consumer
#define MEGA_GRID (DKB_ + 255 + 255 + 1)   // 551

// ---------------------------------------------------------------------------
// Tiled transpose helpers: src R x C row-major -> dst C x R row-major.
// ---------------------------------------------------------------------------
__device__ inline void transpose_tile(const float* __restrict__ src,
                                      float* __restrict__ dst,
                                      int R, int C, int bx, int by, int t,
                                      float (*tile)[33]) {
    int tx = t & 31, ty = t >> 5;      // 32 x 8
    int c0 = bx * 32, r0 = by * 32;
#pragma unroll
    for (int j = 0; j < 4; ++j) {
        int r = r0 + ty + j * 8, c = c0 + tx;
        if (r < R && c < C) tile[ty + j * 8][tx] = src[(size_t)r * C + c];
    }
    __syncthreads();
#pragma unroll
    for (int j = 0; j < 4; ++j) {
        int c = c0 + ty + j * 8, r = r0 + tx;
        if (r < R && c < C) dst[(size_t)c * R + r] = tile[tx][ty + j * 8];
    }
}

__device__ inline void transpose_tile_bf16(const float* __restrict__ src,
                                           __hip_bfloat16* __restrict__ dst,
                                           int R, int C, int bx, int by, int t,
                                           float (*tile)[33]) {
    int tx = t & 31, ty = t >> 5;      // 32 x 8
    int c0 = bx * 32, r0 = by * 32;
#pragma unroll
    for (int j = 0; j < 4; ++j) {
        int r = r0 + ty + j * 8, c = c0 + tx;
        if (r < R && c < C) tile[ty + j * 8][tx] = src[(size_t)r * C + c];
    }
    __syncthreads();
#pragma unroll
    for (int j = 0; j < 4; ++j) {
        int c = c0 + ty + j * 8, r = r0 + tx;
        if (r < R && c < C)
            dst[(size_t)c * R + r] = __float2bfloat16(tile[tx][ty + j * 8]);
    }
}

// ---------------------------------------------------------------------------
// Fused prep: W1(bf16)/x/W2 transposes + mask compaction + sync-state reset.
// ---------------------------------------------------------------------------
__global__ __launch_bounds__(256) void prep_k(const float* __restrict__ W1,
                                              const float* __restrict__ x,
                                              const float* __restrict__ W2,
                                              const float* __restrict__ mask,
                                              __hip_bfloat16* __restrict__ w1bf,
                                              float* __restrict__ xt,
                                              float* __restrict__ w2t,
                                              int* __restrict__ cnt,
                                              unsigned short* __restrict__ idx,
                                              int* __restrict__ ctr,
                                              int* __restrict__ flags) {
    __shared__ float tile[32][33];
    __shared__ int c;
    int bid = blockIdx.x, t = threadIdx.x;

    if (bid == 0) {                    // reset mega_k sync state every call
        if (t == 0) *ctr = 0;
        flags[t] = 0;                  // 256 flags, block is 256 threads
    }

    if (bid < TB_W1) {
        transpose_tile_bf16(W1, w1bf, HID_, N_, bid % 313, bid / 313, t, tile);
    } else if (bid < TB_W1 + TB_X) {
        transpose_tile(x, xt, B_, N_, bid - TB_W1, 0, t, tile);
    } else if (bid < TB_W1 + TB_X + TB_W2) {
        int b = bid - (TB_W1 + TB_X);
        transpose_tile(W2, w2t, 256, HID_, b % 8, b / 8, t, tile);
    } else {
        int g = bid - (TB_W1 + TB_X + TB_W2);
        if (t == 0) c = 0;
        __syncthreads();
        for (int n = t; n < N_; n += 256) {
            if (mask[(size_t)g * N_ + n] != 0.0f) {
                int p = atomicAdd(&c, 1);          // LDS atomic only
                idx[(size_t)g * N_ + p] = (unsigned short)n;
            }
        }
        __syncthreads();
        if (t == 0) cnt[g] = c;
    }
}

// ---------------------------------------------------------------------------
// 16 scalar FMAs: acc[j] (batch 4tb+j) += x[j] * w  (float4 over HID cols)
// ---------------------------------------------------------------------------
__device__ __forceinline__ void fma16(float4& a0, float4& a1, float4& a2,
                                      float4& a3, float4 w, float4 xv) {
    a0.x = fmaf(xv.x, w.x, a0.x); a0.y = fmaf(xv.x, w.y, a0.y);
    a0.z = fmaf(xv.x, w.z, a0.z); a0.w = fmaf(xv.x, w.w, a0.w);
    a1.x = fmaf(xv.y, w.x, a1.x); a1.y = fmaf(xv.y, w.y, a1.y);
    a1.z = fmaf(xv.y, w.z, a1.z); a1.w = fmaf(xv.y, w.w, a1.w);
    a2.x = fmaf(xv.z, w.x, a2.x); a2.y = fmaf(xv.z, w.y, a2.y);
    a2.z = fmaf(xv.z, w.z, a2.z); a2.w = fmaf(xv.z, w.w, a2.w);
    a3.x = fmaf(xv.w, w.x, a3.x); a3.y = fmaf(xv.w, w.y, a3.y);
    a3.z = fmaf(xv.w, w.z, a3.z); a3.w = fmaf(xv.w, w.w, a3.w);
}

// ---------------------------------------------------------------------------
// MEGA kernel — GEMM1(bf16 W, LDS-staged MLP) + BN1 + ReLU + GEMM2 + BN2 + ReLU.
// Roles (block-uniform):
//   bid <  40      : dense producer  (group 255, 250 genes) -> hpartD, ctr++
//   bid 40..294    : sparse producer g, genes [0, c/2)      -> hpartS, flag=1
//   bid 295..549   : sparse consumer g, genes [c/2, c), merge, fused tail
//   bid == 550     : dense consumer: spin ctr, reduce 40 partials, fused tail
// 512 threads: tc=t&63 (float4 col; wave spans full 512B bf16 W-row, coalesced)
//              tb=t>>6 (batches 4tb..4tb+3; x via LDS broadcast).
// launch_bounds(512,4): VGPR<=128 -> 2 blocks/CU -> ~4 waves/SIMD.
// Producers have lower blockIdx than consumers; consumers spin only after
// doing their own half -> forward progress guaranteed.
// ---------------------------------------------------------------------------
__global__ __launch_bounds__(512, 4) void mega_k(const uint2* __restrict__ w1bf,
                                                 const float4* __restrict__ xt4,
                                                 const int* __restrict__ cnt,
                                                 const unsigned short* __restrict__ idx,
                                                 const float4* __restrict__ b1_4,
                                                 const float* __restrict__ g1,
                                                 const float* __restrict__ be1,
                                                 const float4* __restrict__ w2t4,
                                                 const float4* __restrict__ b2_4,
                                                 const float* __restrict__ g2,
                                                 const float* __restrict__ be2,
                                                 float4* __restrict__ hpartD,
                                                 float4* __restrict__ hpartS,
                                                 int* __restrict__ ctr,
                                                 int* __restrict__ flags,
                                                 float4* __restrict__ z4) {
    // ns/xs (phase A) and lh (phases B/C) are phase-disjoint: overlay.
    __shared__ __align__(16) char smem[33280];
    __shared__ float rs[8], rss[8];
    int* ns = (int*)smem;                              // 128 ints
    float4 (*xs)[9] = (float4 (*)[9])(smem + 512);     // 128 x 9 float4
    float (*lh)[260] = (float (*)[260])smem;           // 32 x 260 floats

    const int bid = blockIdx.x, t = threadIdx.x;
    const int tc = t & 63;             // float4 column 0..63
    const int tb = t >> 6;             // wave id -> batches 4tb..4tb+3

    float4 a0 = make_float4(0.f, 0.f, 0.f, 0.f), a1 = a0, a2 = a0, a3 = a0;

    int role, g, k0 = 0, kend = 0;
    if (bid < DKB_) {
        role = 0; g = 255; k0 = bid * DCH_; kend = k0 + DCH_;
    } else if (bid < DKB_ + 255) {
        role = 1; g = bid - DKB_;
        int c = cnt[g]; k0 = 0; kend = c >> 1;
    } else if (bid < DKB_ + 510) {
        role = 2; g = bid - (DKB_ + 255);
        int c = cnt[g]; k0 = c >> 1; kend = c;
    } else {
        role = 3; g = 255;
    }

    if (role <= 2) {
        // ------------- phase A: staged sparse/dense GEMM1 -------------
        for (int base = k0; base < kend; base += 128) {
            int kn = min(128, kend - base);
            __syncthreads();                          // protect ns/xs reuse
            if (t < kn)
                ns[t] = (role == 0) ? (base + t)
                                    : (int)idx[(size_t)g * N_ + base + t];
            __syncthreads();
            for (int i = t; i < kn * 8; i += 512)     // cooperative x gather
                xs[i >> 3][i & 7] = xt4[(size_t)ns[i >> 3] * 8 + (i & 7)];
            __syncthreads();

#pragma unroll 8
            for (int k = 0; k < kn; ++k) {
                int n = ns[k];
                uint2 u = w1bf[(size_t)n * 64 + tc];  // 512B/wave, coalesced
                float4 wv;
                wv.x = __uint_as_float(u.x << 16);    // bf16 -> f32
                wv.y = __uint_as_float(u.x & 0xffff0000u);
                wv.z = __uint_as_float(u.y << 16);
                wv.w = __uint_as_float(u.y & 0xffff0000u);
                float4 xv = xs[k][tb];                // LDS broadcast
                fma16(a0, a1, a2, a3, wv, xv);
            }
        }
    }

    if (role == 0) {
        float4* dst = hpartD + (size_t)bid * 2048;
        dst[(4 * tb + 0) * 64 + tc] = a0;
        dst[(4 * tb + 1) * 64 + tc] = a1;
        dst[(4 * tb + 2) * 64 + tc] = a2;
        dst[(4 * tb + 3) * 64 + tc] = a3;
        __threadfence();
        __syncthreads();
        if (t == 0)
            __hip_atomic_fetch_add(ctr, 1, __ATOMIC_RELEASE,
                                   __HIP_MEMORY_SCOPE_AGENT);
        return;
    } else if (role == 1) {
        float4* dst = hpartS + (size_t)g * 2048;
        dst[(4 * tb + 0) * 64 + tc] = a0;
        dst[(4 * tb + 1) * 64 + tc] = a1;
        dst[(4 * tb + 2) * 64 + tc] = a2;
        dst[(4 * tb + 3) * 64 + tc] = a3;
        __threadfence();
        __syncthreads();
        if (t == 0)
            __hip_atomic_store(&flags[g], 1, __ATOMIC_RELEASE,
                               __HIP_MEMORY_SCOPE_AGENT);
        return;
    } else if (role == 2) {
        // own half done; add bias, then wait for producer half and merge
        float4 bb = b1_4[tc];
        a0.x += bb.x; a0.y += bb.y; a0.z += bb.z; a0.w += bb.w;
        a1.x += bb.x; a1.y += bb.y; a1.z += bb.z; a1.w += bb.w;
        a2.x += bb.x; a2.y += bb.y; a2.z += bb.z; a2.w += bb.w;
        a3.x += bb.x; a3.y += bb.y; a3.z += bb.z; a3.w += bb.w;
        if (t == 0) {
            while (__hip_atomic_load(&flags[g], __ATOMIC_ACQUIRE,
                                     __HIP_MEMORY_SCOPE_AGENT) == 0)
                __builtin_amdgcn_s_sleep(1);
            __threadfence();
        }
        __syncthreads();                    // also guards xs -> lh overlay
        const float4* pp = hpartS + (size_t)g * 2048;
        float4 p0 = pp[(4 * tb + 0) * 64 + tc];
        float4 p1 = pp[(4 * tb + 1) * 64 + tc];
        float4 p2 = pp[(4 * tb + 2) * 64 + tc];
        float4 p3 = pp[(4 * tb + 3) * 64 + tc];
        a0.x += p0.x; a0.y += p0.y; a0.z += p0.z; a0.w += p0.w;
        a1.x += p1.x; a1.y += p1.y; a1.z += p1.z; a1.w += p1.w;
        a2.x += p2.x; a2.y += p2.y; a2.z += p2.z; a2.w += p2.w;
        a3.x += p3.x; a3.y += p3.y; a3.z += p3.z; a3.w += p3.w;
    } else {
        // dense consumer: reduce 40 partials
        if (t == 0) {
            while (__hip_atomic_load(ctr, __ATOMIC_ACQUIRE,
                                     __HIP_MEMORY_SCOPE_AGENT) < DKB_)
                __builtin_amdgcn_s_sleep(1);
            __threadfence();
        }
        __syncthreads();
        float4 bb = b1_4[tc];
        a0 = bb; a1 = bb; a2 = bb; a3 = bb;
#pragma unroll 4
        for (int kb = 0; kb < DKB_; ++kb) {
            const float4* pp = hpartD + (size_t)kb * 2048 + (4 * tb) * 64 + tc;
            float4 v0 = pp[0], v1 = pp[64], v2 = pp[128], v3 = pp[192];
            a0.x += v0.x; a0.y += v0.y; a0.z += v0.z; a0.w += v0.w;
            a1.x += v1.x; a1.y += v1.y; a1.z += v1.z; a1.w += v1.w;
            a2.x += v2.x; a2.y += v2.y; a2.z += v2.z; a2.w += v2.w;
            a3.x += v3.x; a3.y += v3.y; a3.z += v3.z; a3.w += v3.w;
        }
    }

    // ---------------- phase B: BN1 stats (from registers) ----------------
    float s = 0.f, ss = 0.f;
    {
        float4 aa[4] = {a0, a1, a2, a3};
#pragma unroll
        for (int j = 0; j < 4; ++j) {
            s  += aa[j].x + aa[j].y + aa[j].z + aa[j].w;
            ss += aa[j].x * aa[j].x + aa[j].y * aa[j].y
                + aa[j].z * aa[j].z + aa[j].w * aa[j].w;
        }
    }
#pragma unroll
    for (int o = 32; o > 0; o >>= 1) { s += __shfl_down(s, o); ss += __shfl_down(ss, o); }
    if (tc == 0) { rs[tb] = s; rss[tb] = ss; }
    __syncthreads();
    float S = 0.f, SS = 0.f;
#pragma unroll
    for (int j = 0; j < 8; ++j) { S += rs[j]; SS += rss[j]; }
    const float inv = 1.0f / (float)(B_ * HID_);
    float mean = S * inv;
    float var  = SS * inv - mean * mean;       // biased, matches jnp.var
    float sc = g1[g] * rsqrtf(var + EPS_);
    float sh = be1[g] - mean * sc;

    // normalize + ReLU own elements -> LDS (overlays xs; barrier above passed)
    {
        float4 aa[4] = {a0, a1, a2, a3};
#pragma unroll
        for (int j = 0; j < 4; ++j) {
            float4 v;
            v.x = fmaxf(fmaf(aa[j].x, sc, sh), 0.f);
            v.y = fmaxf(fmaf(aa[j].y, sc, sh), 0.f);
            v.z = fmaxf(fmaf(aa[j].z, sc, sh), 0.f);
            v.w = fmaxf(fmaf(aa[j].w, sc, sh), 0.f);
            *(float4*)&lh[4 * tb + j][4 * tc] = v;
        }
    }
    __syncthreads();

    // ---------------- phase C: GEMM2 + BN2 + ReLU ----------------
    float4 bb2 = b2_4[tc];
    float4 c0 = bb2, c1 = bb2, c2 = bb2, c3 = bb2;
#pragma unroll 8
    for (int k = 0; k < HID_; ++k) {
        float4 wv = w2t4[(size_t)k * 64 + tc];         // 1KB/wave, coalesced
        float x0 = lh[4 * tb + 0][k];                  // LDS broadcast
        float x1 = lh[4 * tb + 1][k];
        float x2 = lh[4 * tb + 2][k];
        float x3 = lh[4 * tb + 3][k];
        c0.x = fmaf(x0, wv.x, c0.x); c0.y = fmaf(x0, wv.y, c0.y);
        c0.z = fmaf(x0, wv.z, c0.z); c0.w = fmaf(x0, wv.w, c0.w);
        c1.x = fmaf(x1, wv.x, c1.x); c1.y = fmaf(x1, wv.y, c1.y);
        c1.z = fmaf(x1, wv.z, c1.z); c1.w = fmaf(x1, wv.w, c1.w);
        c2.x = fmaf(x2, wv.x, c2.x); c2.y = fmaf(x2, wv.y, c2.y);
        c2.z = fmaf(x2, wv.z, c2.z); c2.w = fmaf(x2, wv.w, c2.w);
        c3.x = fmaf(x3, wv.x, c3.x); c3.y = fmaf(x3, wv.y, c3.y);
        c3.z = fmaf(x3, wv.z, c3.z); c3.w = fmaf(x3, wv.w, c3.w);
    }

    s = 0.f; ss = 0.f;
    {
        float4 cc[4] = {c0, c1, c2, c3};
#pragma unroll
        for (int j = 0; j < 4; ++j) {
            s  += cc[j].x + cc[j].y + cc[j].z + cc[j].w;
            ss += cc[j].x * cc[j].x + cc[j].y * cc[j].y
                + cc[j].z * cc[j].z + cc[j].w * cc[j].w;
        }
    }
#pragma unroll
    for (int o = 32; o > 0; o >>= 1) { s += __shfl_down(s, o); ss += __shfl_down(ss, o); }
    if (tc == 0) { rs[tb] = s; rss[tb] = ss; }   // safe: BN1 reads pre-barrier
    __syncthreads();
    S = 0.f; SS = 0.f;
#pragma unroll
    for (int j = 0; j < 8; ++j) { S += rs[j]; SS += rss[j]; }
    mean = S * inv;
    var  = SS * inv - mean * mean;
    float sc2 = g2[g] * rsqrtf(var + EPS_);
    float sh2 = be2[g] - mean * sc2;

    {
        float4 cc[4] = {c0, c1, c2, c3};
#pragma unroll
        for (int j = 0; j < 4; ++j) {
            int b = 4 * tb + j;
            float4 v;
            v.x = fmaxf(fmaf(cc[j].x, sc2, sh2), 0.f);
            v.y = fmaxf(fmaf(cc[j].y, sc2, sh2), 0.f);
            v.z = fmaxf(fmaf(cc[j].z, sc2, sh2), 0.f);
            v.w = fmaxf(fmaf(cc[j].w, sc2, sh2), 0.f);
            z4[(size_t)(b * G_ + g) * 64 + tc] = v;
        }
    }
}

// ---------------------------------------------------------------------------
extern "C" void kernel_launch(void* const* d_in, const int* in_sizes, int n_in,
                              void* d_out, int out_size, void* d_ws, size_t ws_size,
                              hipStream_t stream) {
    const float* x    = (const float*)d_in[0];
    const float* mask = (const float*)d_in[1];
    const float* W1   = (const float*)d_in[2];
    const float* b1   = (const float*)d_in[3];
    const float* g1   = (const float*)d_in[4];
    const float* be1  = (const float*)d_in[5];
    const float* W2   = (const float*)d_in[6];
    const float* b2   = (const float*)d_in[7];
    const float* g2   = (const float*)d_in[8];
    const float* be2  = (const float*)d_in[9];
    float* out = (float*)d_out;

    char* ws = (char*)d_ws;
    size_t off = 0;
    auto take = [&](size_t bytes) {
        char* p = ws + off;
        off = (off + bytes + 255) & ~(size_t)255;
        return p;
    };
    __hip_bfloat16* w1bf = (__hip_bfloat16*)take((size_t)N_ * HID_ * 2);  // (N, HID) bf16
    float* xt            = (float*)take((size_t)N_ * B_ * 4);             // (N, B)
    float* w2t           = (float*)take((size_t)HID_ * HID_ * 4);         // (HID, Z)
    float* hpartD        = (float*)take((size_t)DKB_ * B_ * HID_ * 4);
    float* hpartS        = (float*)take((size_t)255 * B_ * HID_ * 4);
    int* cnt             = (int*)take((size_t)G_ * 4);
    unsigned short* idx  = (unsigned short*)take((size_t)G_ * N_ * 2);
    int* ctr             = (int*)take(256);
    int* flags           = (int*)take((size_t)256 * 4);

    prep_k<<<PREP_GRID, 256, 0, stream>>>(W1, x, W2, mask, w1bf, xt, w2t,
                                          cnt, idx, ctr, flags);
    mega_k<<<MEGA_GRID, 512, 0, stream>>>((const uint2*)w1bf, (const float4*)xt,
                                          cnt, idx, (const float4*)b1,
                                          g1, be1,
                                          (const float4*)w2t, (const float4*)b2,
                                          g2, be2,
                                          (float4*)hpartD, (float4*)hpartS,
                                          ctr, flags, (float4*)out);
}

// Round 9
// 84.888 us; speedup vs baseline: 2.2356x; 1.8629x over previous
//
#include <hip/hip_runtime.h>
#include <hip/hip_bf16.h>

#define B_    32
#define N_    10000
#define G_    256
#define HID_  256
#define EPS_  1e-5f
#define TILE_ 256              // genes staged per LDS tile

// prep_k grid segmentation
#define TB_W1  2504            // 313 col-tiles x 8 row-tiles (W1: 256 x 10000)
#define TB_X   313             // x: 32 x 10000
#define TB_W2  64              // W2: 256 x 256
#define NB_CMP 256             // mask compaction, one block per g
#define PREP_GRID (TB_W1 + TB_X + TB_W2 + NB_CMP)   // 3137

#define DKB_  40               // dense-group split-K producer blocks
#define DCH_  250              // genes per dense chunk (40*250 = 10000)
#define MEGA_GRID (DKB_ + 255 + 1)   // 296

// ---------------------------------------------------------------------------
// Tiled transpose helpers: src R x C row-major -> dst C x R row-major.
// ---------------------------------------------------------------------------
__device__ inline void transpose_tile(const float* __restrict__ src,
                                      float* __restrict__ dst,
                                      int R, int C, int bx, int by, int t,
                                      float (*tile)[33]) {
    int tx = t & 31, ty = t >> 5;      // 32 x 8
    int c0 = bx * 32, r0 = by * 32;
#pragma unroll
    for (int j = 0; j < 4; ++j) {
        int r = r0 + ty + j * 8, c = c0 + tx;
        if (r < R && c < C) tile[ty + j * 8][tx] = src[(size_t)r * C + c];
    }
    __syncthreads();
#pragma unroll
    for (int j = 0; j < 4; ++j) {
        int c = c0 + ty + j * 8, r = r0 + tx;
        if (r < R && c < C) dst[(size_t)c * R + r] = tile[tx][ty + j * 8];
    }
}

__device__ inline void transpose_tile_bf16(const float* __restrict__ src,
                                           __hip_bfloat16* __restrict__ dst,
                                           int R, int C, int bx, int by, int t,
                                           float (*tile)[33]) {
    int tx = t & 31, ty = t >> 5;      // 32 x 8
    int c0 = bx * 32, r0 = by * 32;
#pragma unroll
    for (int j = 0; j < 4; ++j) {
        int r = r0 + ty + j * 8, c = c0 + tx;
        if (r < R && c < C) tile[ty + j * 8][tx] = src[(size_t)r * C + c];
    }
    __syncthreads();
#pragma unroll
    for (int j = 0; j < 4; ++j) {
        int c = c0 + ty + j * 8, r = r0 + tx;
        if (r < R && c < C)
            dst[(size_t)c * R + r] = __float2bfloat16(tile[tx][ty + j * 8]);
    }
}

// ---------------------------------------------------------------------------
// Fused prep: W1(bf16)/x/W2 transposes + mask compaction + ctr reset.
// ---------------------------------------------------------------------------
__global__ __launch_bounds__(256) void prep_k(const float* __restrict__ W1,
                                              const float* __restrict__ x,
                                              const float* __restrict__ W2,
                                              const float* __restrict__ mask,
                                              __hip_bfloat16* __restrict__ w1bf,
                                              float* __restrict__ xt,
                                              float* __restrict__ w2t,
                                              int* __restrict__ cnt,
                                              unsigned short* __restrict__ idx,
                                              int* __restrict__ ctr) {
    __shared__ float tile[32][33];
    __shared__ int c;
    int bid = blockIdx.x, t = threadIdx.x;

    if (bid == 0 && t == 0) *ctr = 0;  // reset mega_k producer counter

    if (bid < TB_W1) {
        transpose_tile_bf16(W1, w1bf, HID_, N_, bid % 313, bid / 313, t, tile);
    } else if (bid < TB_W1 + TB_X) {
        transpose_tile(x, xt, B_, N_, bid - TB_W1, 0, t, tile);
    } else if (bid < TB_W1 + TB_X + TB_W2) {
        int b = bid - (TB_W1 + TB_X);
        transpose_tile(W2, w2t, 256, HID_, b % 8, b / 8, t, tile);
    } else {
        int g = bid - (TB_W1 + TB_X + TB_W2);
        if (t == 0) c = 0;
        __syncthreads();
        for (int n = t; n < N_; n += 256) {
            if (mask[(size_t)g * N_ + n] != 0.0f) {
                int p = atomicAdd(&c, 1);          // LDS atomic only
                idx[(size_t)g * N_ + p] = (unsigned short)n;
            }
        }
        __syncthreads();
        if (t == 0) cnt[g] = c;
    }
}

// ---------------------------------------------------------------------------
// 16 scalar FMAs: acc[j] += x-component j * w  (float4 over 4 HID cols)
// ---------------------------------------------------------------------------
__device__ __forceinline__ void fma16(float4& a0, float4& a1, float4& a2,
                                      float4& a3, float4 w, float4 xv) {
    a0.x = fmaf(xv.x, w.x, a0.x); a0.y = fmaf(xv.x, w.y, a0.y);
    a0.z = fmaf(xv.x, w.z, a0.z); a0.w = fmaf(xv.x, w.w, a0.w);
    a1.x = fmaf(xv.y, w.x, a1.x); a1.y = fmaf(xv.y, w.y, a1.y);
    a1.z = fmaf(xv.y, w.z, a1.z); a1.w = fmaf(xv.y, w.w, a1.w);
    a2.x = fmaf(xv.z, w.x, a2.x); a2.y = fmaf(xv.z, w.y, a2.y);
    a2.z = fmaf(xv.z, w.z, a2.z); a2.w = fmaf(xv.z, w.w, a2.w);
    a3.x = fmaf(xv.w, w.x, a3.x); a3.y = fmaf(xv.w, w.y, a3.y);
    a3.z = fmaf(xv.w, w.z, a3.z); a3.w = fmaf(xv.w, w.w, a3.w);
}

// ---------------------------------------------------------------------------
// MEGA kernel (round-6 structure + K-half wave split + bf16 W1):
//   bid <  40  : dense producer (group 255, 250 genes) -> hpartD, ctr++
//   bid 40..294: sparse group g = bid-40, fully fused in-block
//   bid == 295 : dense consumer: spin ctr, reduce 40 partials, fused tail
// GEMM1 wave mapping (512 thr = 8 waves): kh = w>>2 (K half), bh = w&3
//   (batches 8bh..8bh+7). tc = t&63 = float4 HID column; a wave's 64 lanes
//   span the full 512B bf16 W-row (coalesced); 32 FMA/thread per load.
// K-halves merge through lh (LDS) inside the block, then the tail runs in
// the 4-batch mapping (tb=t>>6) identical to round 6.
// ---------------------------------------------------------------------------
__global__ __launch_bounds__(512, 4) void mega_k(const uint2* __restrict__ w1bf,
                                                 const float4* __restrict__ xt4,
                                                 const int* __restrict__ cnt,
                                                 const unsigned short* __restrict__ idx,
                                                 const float4* __restrict__ b1_4,
                                                 const float* __restrict__ g1,
                                                 const float* __restrict__ be1,
                                                 const float4* __restrict__ w2t4,
                                                 const float4* __restrict__ b2_4,
                                                 const float* __restrict__ g2,
                                                 const float* __restrict__ be2,
                                                 float4* __restrict__ hpartD,
                                                 int* __restrict__ ctr,
                                                 float4* __restrict__ z4) {
    // GEMM1 staging (ns+xs) and lh are phase-disjoint; lh also serves as the
    // K-half merge buffer. Layout: [0,1K) ns | [1K, 1K+36.9K) xs ; lh at [0,33.3K).
    __shared__ __align__(16) char smem[38912];
    __shared__ float rs[8], rss[8];
    int* ns = (int*)smem;                              // 256 ints
    float4 (*xs)[9] = (float4 (*)[9])(smem + 1024);    // 256 x 9 float4 (pad)
    float (*lh)[260] = (float (*)[260])smem;           // 32 x 260 floats

    const int bid = blockIdx.x, t = threadIdx.x;
    const int tc = t & 63;             // float4 column 0..63
    const int w  = t >> 6;             // wave id
    const int kh = w >> 2;             // K half (GEMM1)
    const int bh = w & 3;              // batch group: batches 8bh..8bh+7
    const int tb = w;                  // tail row group: rows 4tb..4tb+3

    const bool producer = (bid < DKB_);
    const bool sparse   = (bid >= DKB_ && bid < DKB_ + 255);
    const int g = sparse ? (bid - DKB_) : 255;

    float4 a0, a1, a2, a3;             // tail registers (4-batch mapping)

    if (producer || sparse) {
        // ---------------- phase A: GEMM1, K-half x 8-batch waves ----------
        float4 b0 = make_float4(0.f, 0.f, 0.f, 0.f), b1v = b0, b2v = b0, b3v = b0;
        float4 b4 = b0, b5 = b0, b6 = b0, b7 = b0;
        int k0 = producer ? bid * DCH_ : 0;
        int kend = producer ? k0 + DCH_ : cnt[g];

        for (int base = k0; base < kend; base += TILE_) {
            int kn = min(TILE_, kend - base);
            __syncthreads();                       // protect ns/xs reuse
            if (t < kn)
                ns[t] = producer ? (base + t)
                                 : (int)idx[(size_t)g * N_ + base + t];
            __syncthreads();
            for (int i = t; i < kn * 8; i += 512)  // cooperative x gather
                xs[i >> 3][i & 7] = xt4[(size_t)ns[i >> 3] * 8 + (i & 7)];
            __syncthreads();

            int half = (kn + 1) >> 1;
            int ks = kh ? half : 0;
            int ke = kh ? kn : half;
#pragma unroll 8
            for (int k = ks; k < ke; ++k) {
                int n = ns[k];
                uint2 u = w1bf[(size_t)n * 64 + tc];   // 512B/wave, coalesced
                float4 wv;
                wv.x = __uint_as_float(u.x << 16);     // bf16 -> f32
                wv.y = __uint_as_float(u.x & 0xffff0000u);
                wv.z = __uint_as_float(u.y << 16);
                wv.w = __uint_as_float(u.y & 0xffff0000u);
                float4 xa = xs[k][2 * bh];             // LDS broadcast
                float4 xb = xs[k][2 * bh + 1];
                fma16(b0, b1v, b2v, b3v, wv, xa);
                fma16(b4, b5, b6, b7, wv, xb);
            }
        }
        __syncthreads();                   // xs reads done; lh may overlay

        // ---- merge K halves through lh ----
        if (kh == 1) {
            *(float4*)&lh[8 * bh + 0][4 * tc] = b0;
            *(float4*)&lh[8 * bh + 1][4 * tc] = b1v;
            *(float4*)&lh[8 * bh + 2][4 * tc] = b2v;
            *(float4*)&lh[8 * bh + 3][4 * tc] = b3v;
            *(float4*)&lh[8 * bh + 4][4 * tc] = b4;
            *(float4*)&lh[8 * bh + 5][4 * tc] = b5;
            *(float4*)&lh[8 * bh + 6][4 * tc] = b6;
            *(float4*)&lh[8 * bh + 7][4 * tc] = b7;
        }
        __syncthreads();
        if (kh == 0) {
            float4 m[8] = {b0, b1v, b2v, b3v, b4, b5, b6, b7};
            float4 bb = sparse ? b1_4[tc] : make_float4(0.f, 0.f, 0.f, 0.f);
#pragma unroll
            for (int j = 0; j < 8; ++j) {
                float4 p = *(float4*)&lh[8 * bh + j][4 * tc];
                m[j].x += p.x + bb.x; m[j].y += p.y + bb.y;
                m[j].z += p.z + bb.z; m[j].w += p.w + bb.w;
            }
            if (producer) {
                float4* dst = hpartD + (size_t)bid * 2048;
#pragma unroll
                for (int j = 0; j < 8; ++j)
                    dst[(size_t)(8 * bh + j) * 64 + tc] = m[j];
            } else {
#pragma unroll
                for (int j = 0; j < 8; ++j)
                    *(float4*)&lh[8 * bh + j][4 * tc] = m[j];
            }
        }
        if (producer) {
            __threadfence();
            __syncthreads();
            if (t == 0)
                __hip_atomic_fetch_add(ctr, 1, __ATOMIC_RELEASE,
                                       __HIP_MEMORY_SCOPE_AGENT);
            return;
        }
        __syncthreads();
        // redistribute to 4-batch tail mapping
        a0 = *(float4*)&lh[4 * tb + 0][4 * tc];
        a1 = *(float4*)&lh[4 * tb + 1][4 * tc];
        a2 = *(float4*)&lh[4 * tb + 2][4 * tc];
        a3 = *(float4*)&lh[4 * tb + 3][4 * tc];
    } else {
        // ---------------- dense consumer: reduce 40 partials ----------------
        if (t == 0) {
            while (__hip_atomic_load(ctr, __ATOMIC_ACQUIRE,
                                     __HIP_MEMORY_SCOPE_AGENT) < DKB_)
                __builtin_amdgcn_s_sleep(1);
            __threadfence();
        }
        __syncthreads();
        float4 bb = b1_4[tc];
        a0 = bb; a1 = bb; a2 = bb; a3 = bb;
#pragma unroll 4
        for (int kb = 0; kb < DKB_; ++kb) {
            const float4* pp = hpartD + (size_t)kb * 2048 + (4 * tb) * 64 + tc;
            float4 v0 = pp[0], v1 = pp[64], v2 = pp[128], v3 = pp[192];
            a0.x += v0.x; a0.y += v0.y; a0.z += v0.z; a0.w += v0.w;
            a1.x += v1.x; a1.y += v1.y; a1.z += v1.z; a1.w += v1.w;
            a2.x += v2.x; a2.y += v2.y; a2.z += v2.z; a2.w += v2.w;
            a3.x += v3.x; a3.y += v3.y; a3.z += v3.z; a3.w += v3.w;
        }
    }

    // ---------------- phase B: BN1 stats (from registers) ----------------
    float s = 0.f, ss = 0.f;
    {
        float4 aa[4] = {a0, a1, a2, a3};
#pragma unroll
        for (int j = 0; j < 4; ++j) {
            s  += aa[j].x + aa[j].y + aa[j].z + aa[j].w;
            ss += aa[j].x * aa[j].x + aa[j].y * aa[j].y
                + aa[j].z * aa[j].z + aa[j].w * aa[j].w;
        }
    }
#pragma unroll
    for (int o = 32; o > 0; o >>= 1) { s += __shfl_down(s, o); ss += __shfl_down(ss, o); }
    if (tc == 0) { rs[w] = s; rss[w] = ss; }
    __syncthreads();
    float S = 0.f, SS = 0.f;
#pragma unroll
    for (int j = 0; j < 8; ++j) { S += rs[j]; SS += rss[j]; }
    const float inv = 1.0f / (float)(B_ * HID_);
    float mean = S * inv;
    float var  = SS * inv - mean * mean;       // biased, matches jnp.var
    float sc = g1[g] * rsqrtf(var + EPS_);
    float sh = be1[g] - mean * sc;

    // normalize + ReLU own elements -> lh (same cells read above; barrier'd)
    {
        float4 aa[4] = {a0, a1, a2, a3};
#pragma unroll
        for (int j = 0; j < 4; ++j) {
            float4 v;
            v.x = fmaxf(fmaf(aa[j].x, sc, sh), 0.f);
            v.y = fmaxf(fmaf(aa[j].y, sc, sh), 0.f);
            v.z = fmaxf(fmaf(aa[j].z, sc, sh), 0.f);
            v.w = fmaxf(fmaf(aa[j].w, sc, sh), 0.f);
            *(float4*)&lh[4 * tb + j][4 * tc] = v;
        }
    }
    __syncthreads();

    // ---------------- phase C: GEMM2 + BN2 + ReLU ----------------
    float4 bb2 = b2_4[tc];
    float4 c0 = bb2, c1 = bb2, c2 = bb2, c3 = bb2;
#pragma unroll 8
    for (int k = 0; k < HID_; ++k) {
        float4 wv = w2t4[(size_t)k * 64 + tc];         // 1KB/wave, coalesced
        float x0 = lh[4 * tb + 0][k];                  // LDS broadcast
        float x1 = lh[4 * tb + 1][k];
        float x2 = lh[4 * tb + 2][k];
        float x3 = lh[4 * tb + 3][k];
        c0.x = fmaf(x0, wv.x, c0.x); c0.y = fmaf(x0, wv.y, c0.y);
        c0.z = fmaf(x0, wv.z, c0.z); c0.w = fmaf(x0, wv.w, c0.w);
        c1.x = fmaf(x1, wv.x, c1.x); c1.y = fmaf(x1, wv.y, c1.y);
        c1.z = fmaf(x1, wv.z, c1.z); c1.w = fmaf(x1, wv.w, c1.w);
        c2.x = fmaf(x2, wv.x, c2.x); c2.y = fmaf(x2, wv.y, c2.y);
        c2.z = fmaf(x2, wv.z, c2.z); c2.w = fmaf(x2, wv.w, c2.w);
        c3.x = fmaf(x3, wv.x, c3.x); c3.y = fmaf(x3, wv.y, c3.y);
        c3.z = fmaf(x3, wv.z, c3.z); c3.w = fmaf(x3, wv.w, c3.w);
    }

    s = 0.f; ss = 0.f;
    {
        float4 cc[4] = {c0, c1, c2, c3};
#pragma unroll
        for (int j = 0; j < 4; ++j) {
            s  += cc[j].x + cc[j].y + cc[j].z + cc[j].w;
            ss += cc[j].x * cc[j].x + cc[j].y * cc[j].y
                + cc[j].z * cc[j].z + cc[j].w * cc[j].w;
        }
    }
#pragma unroll
    for (int o = 32; o > 0; o >>= 1) { s += __shfl_down(s, o); ss += __shfl_down(ss, o); }
    if (tc == 0) { rs[w] = s; rss[w] = ss; }   // safe: BN1 reads pre-barrier
    __syncthreads();
    S = 0.f; SS = 0.f;
#pragma unroll
    for (int j = 0; j < 8; ++j) { S += rs[j]; SS += rss[j]; }
    mean = S * inv;
    var  = SS * inv - mean * mean;
    float sc2 = g2[g] * rsqrtf(var + EPS_);
    float sh2 = be2[g] - mean * sc2;

    {
        float4 cc[4] = {c0, c1, c2, c3};
#pragma unroll
        for (int j = 0; j < 4; ++j) {
            int b = 4 * tb + j;
            float4 v;
            v.x = fmaxf(fmaf(cc[j].x, sc2, sh2), 0.f);
            v.y = fmaxf(fmaf(cc[j].y, sc2, sh2), 0.f);
            v.z = fmaxf(fmaf(cc[j].z, sc2, sh2), 0.f);
            v.w = fmaxf(fmaf(cc[j].w, sc2, sh2), 0.f);
            z4[(size_t)(b * G_ + g) * 64 + tc] = v;
        }
    }
}

// ---------------------------------------------------------------------------
extern "C" void kernel_launch(void* const* d_in, const int* in_sizes, int n_in,
                              void* d_out, int out_size, void* d_ws, size_t ws_size,
                              hipStream_t stream) {
    const float* x    = (const float*)d_in[0];
    const float* mask = (const float*)d_in[1];
    const float* W1   = (const float*)d_in[2];
    const float* b1   = (const float*)d_in[3];
    const float* g1   = (const float*)d_in[4];
    const float* be1  = (const float*)d_in[5];
    const float* W2   = (const float*)d_in[6];
    const float* b2   = (const float*)d_in[7];
    const float* g2   = (const float*)d_in[8];
    const float* be2  = (const float*)d_in[9];
    float* out = (float*)d_out;

    char* ws = (char*)d_ws;
    size_t off = 0;
    auto take = [&](size_t bytes) {
        char* p = ws + off;
        off = (off + bytes + 255) & ~(size_t)255;
        return p;
    };
    __hip_bfloat16* w1bf = (__hip_bfloat16*)take((size_t)N_ * HID_ * 2);  // (N, HID) bf16
    float* xt            = (float*)take((size_t)N_ * B_ * 4);             // (N, B)
    float* w2t           = (float*)take((size_t)HID_ * HID_ * 4);         // (HID, Z)
    float* hpartD        = (float*)take((size_t)DKB_ * B_ * HID_ * 4);
    int* cnt             = (int*)take((size_t)G_ * 4);
    unsigned short* idx  = (unsigned short*)take((size_t)G_ * N_ * 2);
    int* ctr             = (int*)take(256);

    prep_k<<<PREP_GRID, 256, 0, stream>>>(W1, x, W2, mask, w1bf, xt, w2t,
                                          cnt, idx, ctr);
    mega_k<<<MEGA_GRID, 512, 0, stream>>>((const uint2*)w1bf, (const float4*)xt,
                                          cnt, idx, (const float4*)b1,
                                          g1, be1,
                                          (const float4*)w2t, (const float4*)b2,
                                          g2, be2,
                                          (float4*)hpartD, ctr, (float4*)out);
}